// Round 7
// baseline (531.476 us; speedup 1.0000x reference)
//
#include <hip/hip_runtime.h>
#include <math.h>

typedef __attribute__((ext_vector_type(8))) short short8;
typedef __attribute__((ext_vector_type(4))) float f32x4;

__device__ __forceinline__ unsigned short f2bf(float f) {
  unsigned int u = __float_as_uint(f);
  u += 0x7fffu + ((u >> 16) & 1u);
  return (unsigned short)(u >> 16);
}

// branch-free erf-based gelu (A&S 7.1.26, |err|<1.5e-7)
__device__ __forceinline__ float gelu_f(float v) {
  float xa = fabsf(v) * 0.70710678118f;
  float t = __builtin_amdgcn_rcpf(1.f + 0.3275911f * xa);
  float p = t * (0.254829592f +
            t * (-0.284496736f +
            t * (1.421413741f +
            t * (-1.453152027f + t * 1.061405429f))));
  float erfa = 1.f - p * __expf(-xa * xa);
  return 0.5f * v * (1.f + copysignf(erfa, v));
}

// async global->LDS, 16B per lane. LDS dst is wave-uniform base; HW deposits
// lane i at base + i*16. Global side addresses are per-lane arbitrary.
__device__ __forceinline__ void gll16(const unsigned short* g, unsigned short* l) {
  __builtin_amdgcn_global_load_lds(
      (const __attribute__((address_space(1))) unsigned int*)(uintptr_t)g,
      (__attribute__((address_space(3))) unsigned int*)(uintptr_t)l, 16, 0, 0);
}

// ---------------- all fp32 -> bf16 conversions in ONE dispatch ----------------
__global__ __launch_bounds__(256) void cvt_all(
    const float* __restrict__ Wq, const float* __restrict__ Wk,
    const float* __restrict__ Wv, const float* __restrict__ Wo,
    const float* __restrict__ W1, const float* __restrict__ W2,
    const float* __restrict__ x, unsigned short* __restrict__ ws) {
  const int bi = blockIdx.x;
  const float* in;
  unsigned short* out;
  int i;
  if (bi < 4096) {
    const int m = bi >> 10;
    in = (m == 0) ? Wq : (m == 1) ? Wk : (m == 2) ? Wv : Wo;
    out = ws + (size_t)m * (1u << 20);
    i = (bi & 1023) * 256 + threadIdx.x;
  } else if (bi < 8192) {
    in = W1; out = ws + (4u << 20); i = (bi - 4096) * 256 + threadIdx.x;
  } else if (bi < 12288) {
    in = W2; out = ws + (8u << 20); i = (bi - 8192) * 256 + threadIdx.x;
  } else {
    in = x; out = ws + (12u << 20); i = (bi - 12288) * 256 + threadIdx.x;
  }
  float4 f = reinterpret_cast<const float4*>(in)[i];
  ushort4 o;
  o.x = f2bf(f.x); o.y = f2bf(f.y); o.z = f2bf(f.z); o.w = f2bf(f.w);
  reinterpret_cast<ushort4*>(out)[i] = o;
}

// ---------------- 256-wide pipelined GEMM: C = A[M,K] * B[N,K]^T ------------
// BM=256, BK=64, 512 thr = 8 waves (2M x 4N), per-wave out 128 x (BN/4).
// ONE barrier + one vmcnt(0) per K-tile (classic dbuf; staging lands under
// this tile's compute). Intra-tile: 4 sub-phases, A-fragments register-
// pipelined (afA/afB) gated by counted lgkmcnt(4). Dependency-split MFMA
// ordering (k-half-0 cluster then k-half-1 cluster).
// Rule #18: every inline-asm lgkmcnt is followed by sched_barrier(0).
// T2: XOR swizzle (slot ^= row&7) — pre-swizzled GLOBAL source + linear
// global_load_lds deposit + same-XOR ds_read (both-sides involution).
#define MFMA_SUB(f0, SA)                                                      \
  {                                                                           \
    __builtin_amdgcn_s_setprio(1);                                            \
    _Pragma("unroll") for (int fi = 0; fi < 2; ++fi) {                        \
      _Pragma("unroll") for (int j = 0; j < NREP; ++j) {                      \
        if constexpr (SWAP) {                                                 \
          acc[(f0) + fi][j] = __builtin_amdgcn_mfma_f32_16x16x32_bf16(        \
              bf[j][0], SA[fi][0], acc[(f0) + fi][j], 0, 0, 0);               \
        } else {                                                              \
          acc[(f0) + fi][j] = __builtin_amdgcn_mfma_f32_16x16x32_bf16(        \
              SA[fi][0], bf[j][0], acc[(f0) + fi][j], 0, 0, 0);               \
        }                                                                     \
      }                                                                       \
    }                                                                         \
    _Pragma("unroll") for (int fi = 0; fi < 2; ++fi) {                        \
      _Pragma("unroll") for (int j = 0; j < NREP; ++j) {                      \
        if constexpr (SWAP) {                                                 \
          acc[(f0) + fi][j] = __builtin_amdgcn_mfma_f32_16x16x32_bf16(        \
              bf[j][1], SA[fi][1], acc[(f0) + fi][j], 0, 0, 0);               \
        } else {                                                              \
          acc[(f0) + fi][j] = __builtin_amdgcn_mfma_f32_16x16x32_bf16(        \
              SA[fi][1], bf[j][1], acc[(f0) + fi][j], 0, 0, 0);               \
        }                                                                     \
      }                                                                       \
    }                                                                         \
    __builtin_amdgcn_s_setprio(0);                                            \
  }

// A-frag f sits at rows f*16 (f = 0..7), LDS row stride 64 elems.
#define READ_AF(SET, f0)                                                      \
  {                                                                           \
    SET[0][0] = *reinterpret_cast<const short8*>(                             \
        &Asc[abase + ((f0) * 16) * 64 + s0]);                                 \
    SET[0][1] = *reinterpret_cast<const short8*>(                             \
        &Asc[abase + ((f0) * 16) * 64 + s1]);                                 \
    SET[1][0] = *reinterpret_cast<const short8*>(                             \
        &Asc[abase + ((f0) * 16 + 16) * 64 + s0]);                            \
    SET[1][1] = *reinterpret_cast<const short8*>(                             \
        &Asc[abase + ((f0) * 16 + 16) * 64 + s1]);                            \
  }

#define READ_BF                                                               \
  _Pragma("unroll") for (int j = 0; j < NREP; ++j) {                          \
    bf[j][0] = *reinterpret_cast<const short8*>(                              \
        &Bsc[bbase + (j * 16) * 64 + s0]);                                    \
    bf[j][1] = *reinterpret_cast<const short8*>(                              \
        &Bsc[bbase + (j * 16) * 64 + s1]);                                    \
  }

#define LGKM(n)                                                               \
  asm volatile("s_waitcnt lgkmcnt(" #n ")" ::: "memory");                     \
  __builtin_amdgcn_sched_barrier(0)

#define MEMFENCE asm volatile("" ::: "memory")
#define BAR __builtin_amdgcn_s_barrier()

template <int EPI, int BN, bool SWAP>
__global__ __launch_bounds__(512, 2) void gemm_big(
    const unsigned short* __restrict__ A, const unsigned short* __restrict__ B,
    const float* __restrict__ bias, const float* __restrict__ bias_k,
    int K, int N, const float* __restrict__ resid,
    unsigned short* __restrict__ outb, float* __restrict__ outf) {
  constexpr int WN = BN / 4;     // per-wave N span (64 or 32)
  constexpr int NREP = WN / 16;  // 4 or 2
  constexpr int BGRP = BN / 64;  // B stage groups (4 or 2)
  __shared__ __align__(16) unsigned short As[2][256 * 64];
  __shared__ __align__(16) unsigned short Bs[2][BN * 64];

  const int t = threadIdx.x;
  const int lane = t & 63, wv = t >> 6;
  const int wm = wv >> 2, wn = wv & 3;
  const int l15 = lane & 15, quad = lane >> 4;

  // XCD-contiguous raster (all grids have nwg % 8 == 0, gridDim.x pow2)
  const int gx = gridDim.x;
  const int nwg = gx * gridDim.y;
  int lin = blockIdx.y * gx + blockIdx.x;
  lin = (lin & 7) * (nwg >> 3) + (lin >> 3);
  const int gxs = 31 - __clz(gx);
  const int tn = (lin & (gx - 1)) * BN;
  const int tm = (lin >> gxs) * 256;

  // staging: global side carries the swizzle, LDS deposit is linear.
  // LDS[r][s*8] <- global(r, (s ^ (r&7))*8); read uses the same XOR.
  const int srow = lane >> 3;                   // 0..7 within wave's 8 rows
  const int scol = ((lane & 7) ^ srow) << 3;    // swizzled 8-elem slot
  const unsigned short* pA[4];
  const unsigned short* pB[BGRP];
#pragma unroll
  for (int g = 0; g < 4; ++g)
    pA[g] = &A[(size_t)(tm + g * 64 + wv * 8 + srow) * K + scol];
#pragma unroll
  for (int g = 0; g < BGRP; ++g)
    pB[g] = &B[(size_t)(tn + g * 64 + wv * 8 + srow) * K + scol];

  // read-side swizzled offsets (elems)
  const int abase = (wm * 128 + l15) * 64;
  const int bbase = (wn * WN + l15) * 64;
  const int s0 = ((quad ^ (l15 & 7)) << 3);
  const int s1 = (((quad + 4) ^ (l15 & 7)) << 3);

  const f32x4 zero = {0.f, 0.f, 0.f, 0.f};
  f32x4 acc[8][NREP];
#pragma unroll
  for (int i = 0; i < 8; ++i)
#pragma unroll
    for (int j = 0; j < NREP; ++j) acc[i][j] = zero;
  short8 afA[2][2], afB[2][2], bf[NREP][2];

  // prologue: stage tile 0 -> buf0
#pragma unroll
  for (int g = 0; g < 4; ++g) {
    gll16(pA[g], &As[0][(g * 64 + wv * 8) * 64]);
    pA[g] += 64;
  }
#pragma unroll
  for (int g = 0; g < BGRP; ++g) {
    gll16(pB[g], &Bs[0][(g * 64 + wv * 8) * 64]);
    pB[g] += 64;
  }
  asm volatile("s_waitcnt vmcnt(0)" ::: "memory");
  BAR;
  MEMFENCE;

  const int NT = K >> 6;
  for (int tt = 0; tt < NT; ++tt) {
    const unsigned short* Asc = As[tt & 1];
    const unsigned short* Bsc = Bs[tt & 1];
    unsigned short* Asn = As[(tt + 1) & 1];
    unsigned short* Bsn = Bs[(tt + 1) & 1];

    // stage tile t+1 into the other buffer (lands under this tile's compute)
    if (tt + 1 < NT) {
#pragma unroll
      for (int g = 0; g < 4; ++g) {
        gll16(pA[g], &Asn[(g * 64 + wv * 8) * 64]);
        pA[g] += 64;
      }
#pragma unroll
      for (int g = 0; g < BGRP; ++g) {
        gll16(pB[g], &Bsn[(g * 64 + wv * 8) * 64]);
        pB[g] += 64;
      }
    }

    // tile-top reads: all B frags + A set A (frags 0,1)
    READ_BF;
    READ_AF(afA, 0);
    // sub 0: prefetch frags 2,3 -> setB; MFMA frags 0,1 (gate: bf+afA landed)
    READ_AF(afB, 2);
    LGKM(4);
    MFMA_SUB(0, afA);
    // sub 1: prefetch frags 4,5 -> setA; MFMA frags 2,3
    READ_AF(afA, 4);
    LGKM(4);
    MFMA_SUB(2, afB);
    // sub 2: prefetch frags 6,7 -> setB; MFMA frags 4,5
    READ_AF(afB, 6);
    LGKM(4);
    MFMA_SUB(4, afA);
    // sub 3: MFMA frags 6,7 (all reads must be done)
    LGKM(0);
    MFMA_SUB(6, afB);

    if (tt + 1 < NT) {
      asm volatile("s_waitcnt vmcnt(0)" ::: "memory");  // t+1 deposits landed
      BAR;  // all waves done reading cur + deposits visible
      MEMFENCE;
    }
  }

  // ---- epilogue ----
  if constexpr (!SWAP) {
    // EPI 4: V epilogue — regs hold 4 consecutive tokens; pack for [b,h,dh,s]
    const int rb2 = tm + wm * 128 + (quad << 2);
    const int cb2 = tn + wn * WN + l15;
#pragma unroll
    for (int i = 0; i < 8; ++i) {
      const int row0 = rb2 + i * 16;
#pragma unroll
      for (int j = 0; j < NREP; ++j) {
        const int col = cb2 + j * 16;
        const float bcol = bias[col];
        const int h = col >> 6, dh = col & 63;
        const int b = row0 >> 10, s0r = row0 & 1023;
        ushort4 pk;
        pk.x = f2bf(acc[i][j][0] + bcol);
        pk.y = f2bf(acc[i][j][1] + bcol);
        pk.z = f2bf(acc[i][j][2] + bcol);
        pk.w = f2bf(acc[i][j][3] + bcol);
        *reinterpret_cast<ushort4*>(
            &outb[(((size_t)((b << 4) + h)) << 16) + (dh << 10) + s0r]) = pk;
      }
    }
  } else {
    const int rb = tm + wm * 128 + l15;
    const int cb = tn + wn * WN + (quad << 2);
#pragma unroll
    for (int i = 0; i < 8; ++i) {
      const int row = rb + i * 16;
#pragma unroll
      for (int j = 0; j < NREP; ++j) {
        const int col0 = cb + j * 16;
        if constexpr (EPI == 5) {
          const int chunk = col0 >> 10;  // 0=Q, 1=K
          const int colc = col0 & 1023;
          const float4 b4 = *reinterpret_cast<const float4*>(
              &(chunk == 0 ? bias : bias_k)[colc]);
          const float sc = (chunk == 0) ? 0.125f : 1.f;
          const int h = colc >> 6, dh = colc & 63;
          const int b = row >> 10, s = row & 1023;
          ushort4 pk;
          pk.x = f2bf((acc[i][j][0] + b4.x) * sc);
          pk.y = f2bf((acc[i][j][1] + b4.y) * sc);
          pk.z = f2bf((acc[i][j][2] + b4.z) * sc);
          pk.w = f2bf((acc[i][j][3] + b4.w) * sc);
          *reinterpret_cast<ushort4*>(
              &outb[((size_t)chunk << 23) + (((size_t)((b << 4) + h)) << 16) +
                    (s << 6) + dh]) = pk;
        } else if constexpr (EPI == 2) {
          const float4 b4 = *reinterpret_cast<const float4*>(&bias[col0]);
          ushort4 pk;
          pk.x = f2bf(gelu_f(acc[i][j][0] + b4.x));
          pk.y = f2bf(gelu_f(acc[i][j][1] + b4.y));
          pk.z = f2bf(gelu_f(acc[i][j][2] + b4.z));
          pk.w = f2bf(gelu_f(acc[i][j][3] + b4.w));
          *reinterpret_cast<ushort4*>(&outb[(size_t)row * (size_t)N + col0]) = pk;
        } else {  // EPI 1: f32 + bias + residual
          const float4 b4 = *reinterpret_cast<const float4*>(&bias[col0]);
          const size_t idx = (size_t)row * (size_t)N + col0;
          const float4 r4 = *reinterpret_cast<const float4*>(&resid[idx]);
          float4 o4;
          o4.x = acc[i][j][0] + b4.x + r4.x;
          o4.y = acc[i][j][1] + b4.y + r4.y;
          o4.z = acc[i][j][2] + b4.z + r4.z;
          o4.w = acc[i][j][3] + b4.w + r4.w;
          *reinterpret_cast<float4*>(&outf[idx]) = o4;
        }
      }
    }
  }
}
#undef MFMA_SUB
#undef READ_AF
#undef READ_BF
#undef LGKM
#undef MEMFENCE
#undef BAR

// ---------------- fused flash attention (128 Q-rows / block) ----------------
// Round 7: NO K/V LDS staging (common-mistake #7: K/V = 2x128KB per (b,h) is
// L2-resident, and all 8 qt-blocks of a head land on the same XCD under the
// (128,8) grid since XCD = (x+128y)%8 = x%8). Fragments are read directly
// from global (L2-hit latency hidden by free-running waves); ZERO barriers in
// the k-loop -> the 4 waves never lockstep, and LDS drops 45KB -> ~13.5KB.
// Per-wave P transpose round-trip via wave-private Ps kept (in-order DS pipe).
__global__ __launch_bounds__(256) void attn_kernel(
    const unsigned short* __restrict__ Q, const unsigned short* __restrict__ Kc,
    const unsigned short* __restrict__ Vg, const int* __restrict__ mask,
    unsigned short* __restrict__ ctx) {
  __shared__ __align__(16) unsigned short Ps[4][16 * 72];
  __shared__ float maskf[1024];
  const int t = threadIdx.x;
  const int bh = blockIdx.x;
  const int qt = blockIdx.y;
  const int b = bh >> 4, h = bh & 15;
  const int lane = t & 63, wv = t >> 6, l15 = lane & 15, quad = lane >> 4;
  const unsigned short* Qp = Q + ((size_t)bh << 16);
  const unsigned short* Kp = Kc + ((size_t)bh << 16);
  const unsigned short* Vp = Vg + ((size_t)bh << 16);

  for (int i = t; i < 1024; i += 256)
    maskf[i] = mask[b * 1024 + i] ? -8.f : -INFINITY;

  // Q A-fragments straight from global (rows qt*128 + wv*32 + g*16 + l15)
  short8 qf[2][2];
#pragma unroll
  for (int g = 0; g < 2; ++g)
#pragma unroll
    for (int hh = 0; hh < 2; ++hh)
      qf[g][hh] = *reinterpret_cast<const short8*>(
          &Qp[(size_t)(qt * 128 + wv * 32 + g * 16 + l15) * 64 + hh * 32 + quad * 8]);

  const f32x4 zero = {0.f, 0.f, 0.f, 0.f};
  float ps[2][4];
  f32x4 o[2][4];
#pragma unroll
  for (int g = 0; g < 2; ++g)
#pragma unroll
    for (int j = 0; j < 4; ++j) { o[g][j] = zero; ps[g][j] = 0.f; }

  __syncthreads();  // maskf ready (only barrier in the kernel)

  unsigned short* Pw = Ps[wv];
  for (int kt = 0; kt < 16; ++kt) {
    float madd[4];
    short8 kf[4][2];
#pragma unroll
    for (int nt = 0; nt < 4; ++nt) {
      const int krow = kt * 64 + nt * 16 + l15;   // key index
      kf[nt][0] = *reinterpret_cast<const short8*>(&Kp[(size_t)krow * 64 + quad * 8]);
      kf[nt][1] = *reinterpret_cast<const short8*>(&Kp[(size_t)krow * 64 + 32 + quad * 8]);
      madd[nt] = maskf[kt * 64 + nt * 16 + l15];
    }
    short8 vf[4][2];
#pragma unroll
    for (int nt = 0; nt < 4; ++nt) {
      const int dh = nt * 16 + l15;               // V^T row = dh ([b,h,dh,s])
      vf[nt][0] = *reinterpret_cast<const short8*>(&Vp[(size_t)dh * 1024 + kt * 64 + quad * 8]);
      vf[nt][1] = *reinterpret_cast<const short8*>(&Vp[(size_t)dh * 1024 + kt * 64 + 32 + quad * 8]);
    }
#pragma unroll
    for (int g = 0; g < 2; ++g) {
      f32x4 s4[4];
      // dependency split: 4 independent k-half-0 MFMAs, then the 4 half-1s
#pragma unroll
      for (int nt = 0; nt < 4; ++nt)
        s4[nt] = __builtin_amdgcn_mfma_f32_16x16x32_bf16(qf[g][0], kf[nt][0], zero, 0, 0, 0);
#pragma unroll
      for (int nt = 0; nt < 4; ++nt)
        s4[nt] = __builtin_amdgcn_mfma_f32_16x16x32_bf16(qf[g][1], kf[nt][1], s4[nt], 0, 0, 0);
#pragma unroll
      for (int nt = 0; nt < 4; ++nt) {
#pragma unroll
        for (int r = 0; r < 4; ++r) {
          float p = __expf(s4[nt][r] + madd[nt]);
          ps[g][r] += p;
          Pw[(quad * 4 + r) * 72 + nt * 16 + l15] = f2bf(p);
        }
      }
      // C-layout -> A-layout via wave-private LDS (in-order per-wave DS pipe)
      short8 pf0 = *reinterpret_cast<const short8*>(&Pw[l15 * 72 + quad * 8]);
      short8 pf1 = *reinterpret_cast<const short8*>(&Pw[l15 * 72 + 32 + quad * 8]);
#pragma unroll
      for (int nt = 0; nt < 4; ++nt)
        o[g][nt] = __builtin_amdgcn_mfma_f32_16x16x32_bf16(pf0, vf[nt][0], o[g][nt], 0, 0, 0);
#pragma unroll
      for (int nt = 0; nt < 4; ++nt)
        o[g][nt] = __builtin_amdgcn_mfma_f32_16x16x32_bf16(pf1, vf[nt][1], o[g][nt], 0, 0, 0);
    }
  }

#pragma unroll
  for (int g = 0; g < 2; ++g)
#pragma unroll
    for (int r = 0; r < 4; ++r) {
      float v = ps[g][r];
#pragma unroll
      for (int off = 8; off >= 1; off >>= 1) v += __shfl_xor(v, off, 64);
      const float inv = 1.f / v;
      const int srow = qt * 128 + wv * 32 + g * 16 + quad * 4 + r;
#pragma unroll
      for (int nt = 0; nt < 4; ++nt) {
        const int dh = nt * 16 + l15;
        ctx[((size_t)b << 20) + ((size_t)srow << 10) + (h << 6) + dh] =
            f2bf(o[g][nt][r] * inv);
      }
    }
}

// ---------------- layer norm (block per row, D=1024) ----------------
__global__ __launch_bounds__(256) void ln_kernel(float* __restrict__ y,
                                                 const float* __restrict__ g,
                                                 const float* __restrict__ be,
                                                 unsigned short* __restrict__ hb) {
  __shared__ float sm[8];
  const int t = threadIdx.x;
  const size_t row = blockIdx.x;
  float* yr = y + (row << 10);
  float v[4];
#pragma unroll
  for (int i = 0; i < 4; ++i) v[i] = yr[t + (i << 8)];
  float s = v[0] + v[1] + v[2] + v[3];
#pragma unroll
  for (int off = 32; off >= 1; off >>= 1) s += __shfl_xor(s, off, 64);
  if ((t & 63) == 0) sm[t >> 6] = s;
  __syncthreads();
  float mu = (sm[0] + sm[1] + sm[2] + sm[3]) * (1.f / 1024.f);
  float q = 0.f;
#pragma unroll
  for (int i = 0; i < 4; ++i) { float d = v[i] - mu; q += d * d; }
#pragma unroll
  for (int off = 32; off >= 1; off >>= 1) q += __shfl_xor(q, off, 64);
  if ((t & 63) == 0) sm[4 + (t >> 6)] = q;
  __syncthreads();
  float var = (sm[4] + sm[5] + sm[6] + sm[7]) * (1.f / 1024.f);
  float rs = rsqrtf(var + 1e-12f);
#pragma unroll
  for (int i = 0; i < 4; ++i) {
    int c = t + (i << 8);
    float o = (v[i] - mu) * rs * g[c] + be[c];
    yr[c] = o;
    if (hb) hb[(row << 10) + c] = f2bf(o);
  }
}

extern "C" void kernel_launch(void* const* d_in, const int* in_sizes, int n_in,
                              void* d_out, int out_size, void* d_ws, size_t ws_size,
                              hipStream_t stream) {
  const float* x   = (const float*)d_in[0];
  const int*   msk = (const int*)d_in[1];
  const float* Wq  = (const float*)d_in[2];
  const float* bq  = (const float*)d_in[3];
  const float* Wk  = (const float*)d_in[4];
  const float* bk  = (const float*)d_in[5];
  const float* Wv  = (const float*)d_in[6];
  const float* bv  = (const float*)d_in[7];
  const float* Wo  = (const float*)d_in[8];
  const float* bo  = (const float*)d_in[9];
  const float* g1  = (const float*)d_in[10];
  const float* be1 = (const float*)d_in[11];
  const float* W1  = (const float*)d_in[12];
  const float* b1  = (const float*)d_in[13];
  const float* W2  = (const float*)d_in[14];
  const float* b2  = (const float*)d_in[15];
  const float* g2  = (const float*)d_in[16];
  const float* be2 = (const float*)d_in[17];
  float* out = (float*)d_out;

  unsigned short* Wqb = (unsigned short*)d_ws;   // Wq|Wk contiguous = fused QK B
  unsigned short* Wvb = Wqb + (2u << 20);
  unsigned short* Wob = Wvb + (1u << 20);
  unsigned short* W1b = Wob + (1u << 20);
  unsigned short* W2b = W1b + (4u << 20);
  unsigned short* xb  = W2b + (4u << 20);
  unsigned short* qb  = xb + (8u << 20);   // q|k contiguous (chunk<<23)
  unsigned short* vb  = qb + (16u << 20);  // V stored [b,h,dh,s]
  unsigned short* ctx = xb;                // reuse (xb dead after QKV GEMMs)
  unsigned short* ffb = xb;                // 32M elems spanning xb+q+k+v
  float* y1 = (float*)(qb + (24u << 20));
  unsigned short* hb = (unsigned short*)(y1 + (8u << 20));

  dim3 blk(256), blk5(512);
  // all conversions, one dispatch
  cvt_all<<<dim3(20480), blk, 0, stream>>>(Wq, Wk, Wv, Wo, W1, W2, x, (unsigned short*)d_ws);
  // QK fused projection; V separate (transposed pack, non-swapped)
  gemm_big<5, 256, true><<<dim3(8, 32), blk5, 0, stream>>>(xb, Wqb, bq, bk, 1024, 2048,
                                                           nullptr, qb, nullptr);
  gemm_big<4, 128, false><<<dim3(8, 32), blk5, 0, stream>>>(xb, Wvb, bv, nullptr, 1024, 1024,
                                                            nullptr, vb, nullptr);
  attn_kernel<<<dim3(128, 8), blk, 0, stream>>>(qb, qb + (8u << 20), vb, msk, ctx);
  // output projection + residual
  gemm_big<1, 128, true><<<dim3(8, 32), blk5, 0, stream>>>(ctx, Wob, bo, nullptr, 1024, 1024,
                                                           x, nullptr, y1);
  ln_kernel<<<dim3(8192), blk, 0, stream>>>(y1, g1, be1, hb);
  // FFN
  gemm_big<2, 256, true><<<dim3(16, 32), blk5, 0, stream>>>(hb, W1b, b1, nullptr, 1024, 4096,
                                                            nullptr, ffb, nullptr);
  gemm_big<1, 128, true><<<dim3(8, 32), blk5, 0, stream>>>(ffb, W2b, b2, nullptr, 4096, 1024,
                                                           y1, nullptr, out);
  ln_kernel<<<dim3(8192), blk, 0, stream>>>(out, g2, be2, nullptr);
}

// Round 8
// 495.084 us; speedup vs baseline: 1.0735x; 1.0735x over previous
//
#include <hip/hip_runtime.h>
#include <math.h>

typedef __attribute__((ext_vector_type(8))) short short8;
typedef __attribute__((ext_vector_type(4))) float f32x4;

__device__ __forceinline__ unsigned short f2bf(float f) {
  unsigned int u = __float_as_uint(f);
  u += 0x7fffu + ((u >> 16) & 1u);
  return (unsigned short)(u >> 16);
}

// branch-free erf-based gelu (A&S 7.1.26, |err|<1.5e-7)
__device__ __forceinline__ float gelu_f(float v) {
  float xa = fabsf(v) * 0.70710678118f;
  float t = __builtin_amdgcn_rcpf(1.f + 0.3275911f * xa);
  float p = t * (0.254829592f +
            t * (-0.284496736f +
            t * (1.421413741f +
            t * (-1.453152027f + t * 1.061405429f))));
  float erfa = 1.f - p * __expf(-xa * xa);
  return 0.5f * v * (1.f + copysignf(erfa, v));
}

// async global->LDS, 16B per lane. LDS dst is wave-uniform base; HW deposits
// lane i at base + i*16. Global side addresses are per-lane arbitrary.
__device__ __forceinline__ void gll16(const unsigned short* g, unsigned short* l) {
  __builtin_amdgcn_global_load_lds(
      (const __attribute__((address_space(1))) unsigned int*)(uintptr_t)g,
      (__attribute__((address_space(3))) unsigned int*)(uintptr_t)l, 16, 0, 0);
}

// ---------------- all fp32 -> bf16 conversions in ONE dispatch ----------------
__global__ __launch_bounds__(256) void cvt_all(
    const float* __restrict__ Wq, const float* __restrict__ Wk,
    const float* __restrict__ Wv, const float* __restrict__ Wo,
    const float* __restrict__ W1, const float* __restrict__ W2,
    const float* __restrict__ x, unsigned short* __restrict__ ws) {
  const int bi = blockIdx.x;
  const float* in;
  unsigned short* out;
  int i;
  if (bi < 4096) {
    const int m = bi >> 10;
    in = (m == 0) ? Wq : (m == 1) ? Wk : (m == 2) ? Wv : Wo;
    out = ws + (size_t)m * (1u << 20);
    i = (bi & 1023) * 256 + threadIdx.x;
  } else if (bi < 8192) {
    in = W1; out = ws + (4u << 20); i = (bi - 4096) * 256 + threadIdx.x;
  } else if (bi < 12288) {
    in = W2; out = ws + (8u << 20); i = (bi - 8192) * 256 + threadIdx.x;
  } else {
    in = x; out = ws + (12u << 20); i = (bi - 12288) * 256 + threadIdx.x;
  }
  float4 f = reinterpret_cast<const float4*>(in)[i];
  ushort4 o;
  o.x = f2bf(f.x); o.y = f2bf(f.y); o.z = f2bf(f.z); o.w = f2bf(f.w);
  reinterpret_cast<ushort4*>(out)[i] = o;
}

// ---------------- 256-wide pipelined GEMM: C = A[M,K] * B[N,K]^T ------------
// BM=256, BK=64, 512 thr = 8 waves (2M x 4N), per-wave out 128 x (BN/4).
// ONE barrier + one vmcnt(0) per K-tile (classic dbuf; staging lands under
// this tile's compute). Intra-tile: 4 sub-phases, A-fragments register-
// pipelined (afA/afB) gated by counted lgkmcnt(4). Dependency-split MFMA
// ordering (k-half-0 cluster then k-half-1 cluster).
// Rule #18: every inline-asm lgkmcnt is followed by sched_barrier(0).
// T2: XOR swizzle (slot ^= row&7) — pre-swizzled GLOBAL source + linear
// global_load_lds deposit + same-XOR ds_read (both-sides involution).
#define MFMA_SUB(f0, SA)                                                      \
  {                                                                           \
    __builtin_amdgcn_s_setprio(1);                                            \
    _Pragma("unroll") for (int fi = 0; fi < 2; ++fi) {                        \
      _Pragma("unroll") for (int j = 0; j < NREP; ++j) {                      \
        if constexpr (SWAP) {                                                 \
          acc[(f0) + fi][j] = __builtin_amdgcn_mfma_f32_16x16x32_bf16(        \
              bf[j][0], SA[fi][0], acc[(f0) + fi][j], 0, 0, 0);               \
        } else {                                                              \
          acc[(f0) + fi][j] = __builtin_amdgcn_mfma_f32_16x16x32_bf16(        \
              SA[fi][0], bf[j][0], acc[(f0) + fi][j], 0, 0, 0);               \
        }                                                                     \
      }                                                                       \
    }                                                                         \
    _Pragma("unroll") for (int fi = 0; fi < 2; ++fi) {                        \
      _Pragma("unroll") for (int j = 0; j < NREP; ++j) {                      \
        if constexpr (SWAP) {                                                 \
          acc[(f0) + fi][j] = __builtin_amdgcn_mfma_f32_16x16x32_bf16(        \
              bf[j][1], SA[fi][1], acc[(f0) + fi][j], 0, 0, 0);               \
        } else {                                                              \
          acc[(f0) + fi][j] = __builtin_amdgcn_mfma_f32_16x16x32_bf16(        \
              SA[fi][1], bf[j][1], acc[(f0) + fi][j], 0, 0, 0);               \
        }                                                                     \
      }                                                                       \
    }                                                                         \
    __builtin_amdgcn_s_setprio(0);                                            \
  }

// A-frag f sits at rows f*16 (f = 0..7), LDS row stride 64 elems.
#define READ_AF(SET, f0)                                                      \
  {                                                                           \
    SET[0][0] = *reinterpret_cast<const short8*>(                             \
        &Asc[abase + ((f0) * 16) * 64 + s0]);                                 \
    SET[0][1] = *reinterpret_cast<const short8*>(                             \
        &Asc[abase + ((f0) * 16) * 64 + s1]);                                 \
    SET[1][0] = *reinterpret_cast<const short8*>(                             \
        &Asc[abase + ((f0) * 16 + 16) * 64 + s0]);                            \
    SET[1][1] = *reinterpret_cast<const short8*>(                             \
        &Asc[abase + ((f0) * 16 + 16) * 64 + s1]);                            \
  }

#define READ_BF                                                               \
  _Pragma("unroll") for (int j = 0; j < NREP; ++j) {                          \
    bf[j][0] = *reinterpret_cast<const short8*>(                              \
        &Bsc[bbase + (j * 16) * 64 + s0]);                                    \
    bf[j][1] = *reinterpret_cast<const short8*>(                              \
        &Bsc[bbase + (j * 16) * 64 + s1]);                                    \
  }

#define LGKM(n)                                                               \
  asm volatile("s_waitcnt lgkmcnt(" #n ")" ::: "memory");                     \
  __builtin_amdgcn_sched_barrier(0)

#define MEMFENCE asm volatile("" ::: "memory")
#define BAR __builtin_amdgcn_s_barrier()

template <int EPI, int BN, bool SWAP>
__global__ __launch_bounds__(512, 2) void gemm_big(
    const unsigned short* __restrict__ A, const unsigned short* __restrict__ B,
    const float* __restrict__ bias, const float* __restrict__ bias_k,
    int K, int N, const float* __restrict__ resid,
    unsigned short* __restrict__ outb, float* __restrict__ outf) {
  constexpr int WN = BN / 4;     // per-wave N span (64 or 32)
  constexpr int NREP = WN / 16;  // 4 or 2
  constexpr int BGRP = BN / 64;  // B stage groups (4 or 2)
  __shared__ __align__(16) unsigned short As[2][256 * 64];
  __shared__ __align__(16) unsigned short Bs[2][BN * 64];

  const int t = threadIdx.x;
  const int lane = t & 63, wv = t >> 6;
  const int wm = wv >> 2, wn = wv & 3;
  const int l15 = lane & 15, quad = lane >> 4;

  // XCD-contiguous raster (all grids have nwg % 8 == 0, gridDim.x pow2)
  const int gx = gridDim.x;
  const int nwg = gx * gridDim.y;
  int lin = blockIdx.y * gx + blockIdx.x;
  lin = (lin & 7) * (nwg >> 3) + (lin >> 3);
  const int gxs = 31 - __clz(gx);
  const int tn = (lin & (gx - 1)) * BN;
  const int tm = (lin >> gxs) * 256;

  // staging: global side carries the swizzle, LDS deposit is linear.
  // LDS[r][s*8] <- global(r, (s ^ (r&7))*8); read uses the same XOR.
  const int srow = lane >> 3;                   // 0..7 within wave's 8 rows
  const int scol = ((lane & 7) ^ srow) << 3;    // swizzled 8-elem slot
  const unsigned short* pA[4];
  const unsigned short* pB[BGRP];
#pragma unroll
  for (int g = 0; g < 4; ++g)
    pA[g] = &A[(size_t)(tm + g * 64 + wv * 8 + srow) * K + scol];
#pragma unroll
  for (int g = 0; g < BGRP; ++g)
    pB[g] = &B[(size_t)(tn + g * 64 + wv * 8 + srow) * K + scol];

  // read-side swizzled offsets (elems)
  const int abase = (wm * 128 + l15) * 64;
  const int bbase = (wn * WN + l15) * 64;
  const int s0 = ((quad ^ (l15 & 7)) << 3);
  const int s1 = (((quad + 4) ^ (l15 & 7)) << 3);

  const f32x4 zero = {0.f, 0.f, 0.f, 0.f};
  f32x4 acc[8][NREP];
#pragma unroll
  for (int i = 0; i < 8; ++i)
#pragma unroll
    for (int j = 0; j < NREP; ++j) acc[i][j] = zero;
  short8 afA[2][2], afB[2][2], bf[NREP][2];

  // prologue: stage tile 0 -> buf0
#pragma unroll
  for (int g = 0; g < 4; ++g) {
    gll16(pA[g], &As[0][(g * 64 + wv * 8) * 64]);
    pA[g] += 64;
  }
#pragma unroll
  for (int g = 0; g < BGRP; ++g) {
    gll16(pB[g], &Bs[0][(g * 64 + wv * 8) * 64]);
    pB[g] += 64;
  }
  asm volatile("s_waitcnt vmcnt(0)" ::: "memory");
  BAR;
  MEMFENCE;

  const int NT = K >> 6;
  for (int tt = 0; tt < NT; ++tt) {
    const unsigned short* Asc = As[tt & 1];
    const unsigned short* Bsc = Bs[tt & 1];
    unsigned short* Asn = As[(tt + 1) & 1];
    unsigned short* Bsn = Bs[(tt + 1) & 1];

    // stage tile t+1 into the other buffer (lands under this tile's compute)
    if (tt + 1 < NT) {
#pragma unroll
      for (int g = 0; g < 4; ++g) {
        gll16(pA[g], &Asn[(g * 64 + wv * 8) * 64]);
        pA[g] += 64;
      }
#pragma unroll
      for (int g = 0; g < BGRP; ++g) {
        gll16(pB[g], &Bsn[(g * 64 + wv * 8) * 64]);
        pB[g] += 64;
      }
    }

    // tile-top reads: all B frags + A set A (frags 0,1)
    READ_BF;
    READ_AF(afA, 0);
    // sub 0: prefetch frags 2,3 -> setB; MFMA frags 0,1 (gate: bf+afA landed)
    READ_AF(afB, 2);
    LGKM(4);
    MFMA_SUB(0, afA);
    // sub 1: prefetch frags 4,5 -> setA; MFMA frags 2,3
    READ_AF(afA, 4);
    LGKM(4);
    MFMA_SUB(2, afB);
    // sub 2: prefetch frags 6,7 -> setB; MFMA frags 4,5
    READ_AF(afB, 6);
    LGKM(4);
    MFMA_SUB(4, afA);
    // sub 3: MFMA frags 6,7 (all reads must be done)
    LGKM(0);
    MFMA_SUB(6, afB);

    if (tt + 1 < NT) {
      asm volatile("s_waitcnt vmcnt(0)" ::: "memory");  // t+1 deposits landed
      BAR;  // all waves done reading cur + deposits visible
      MEMFENCE;
    }
  }

  // ---- epilogue ----
  if constexpr (!SWAP) {
    // EPI 4: V epilogue — regs hold 4 consecutive tokens; pack for [b,h,dh,s]
    const int rb2 = tm + wm * 128 + (quad << 2);
    const int cb2 = tn + wn * WN + l15;
#pragma unroll
    for (int i = 0; i < 8; ++i) {
      const int row0 = rb2 + i * 16;
#pragma unroll
      for (int j = 0; j < NREP; ++j) {
        const int col = cb2 + j * 16;
        const float bcol = bias[col];
        const int h = col >> 6, dh = col & 63;
        const int b = row0 >> 10, s0r = row0 & 1023;
        ushort4 pk;
        pk.x = f2bf(acc[i][j][0] + bcol);
        pk.y = f2bf(acc[i][j][1] + bcol);
        pk.z = f2bf(acc[i][j][2] + bcol);
        pk.w = f2bf(acc[i][j][3] + bcol);
        *reinterpret_cast<ushort4*>(
            &outb[(((size_t)((b << 4) + h)) << 16) + (dh << 10) + s0r]) = pk;
      }
    }
  } else {
    const int rb = tm + wm * 128 + l15;
    const int cb = tn + wn * WN + (quad << 2);
#pragma unroll
    for (int i = 0; i < 8; ++i) {
      const int row = rb + i * 16;
#pragma unroll
      for (int j = 0; j < NREP; ++j) {
        const int col0 = cb + j * 16;
        if constexpr (EPI == 5) {
          const int chunk = col0 >> 10;  // 0=Q, 1=K
          const int colc = col0 & 1023;
          const float4 b4 = *reinterpret_cast<const float4*>(
              &(chunk == 0 ? bias : bias_k)[colc]);
          const float sc = (chunk == 0) ? 0.125f : 1.f;
          const int h = colc >> 6, dh = colc & 63;
          const int b = row >> 10, s = row & 1023;
          ushort4 pk;
          pk.x = f2bf((acc[i][j][0] + b4.x) * sc);
          pk.y = f2bf((acc[i][j][1] + b4.y) * sc);
          pk.z = f2bf((acc[i][j][2] + b4.z) * sc);
          pk.w = f2bf((acc[i][j][3] + b4.w) * sc);
          *reinterpret_cast<ushort4*>(
              &outb[((size_t)chunk << 23) + (((size_t)((b << 4) + h)) << 16) +
                    (s << 6) + dh]) = pk;
        } else if constexpr (EPI == 2) {
          const float4 b4 = *reinterpret_cast<const float4*>(&bias[col0]);
          ushort4 pk;
          pk.x = f2bf(gelu_f(acc[i][j][0] + b4.x));
          pk.y = f2bf(gelu_f(acc[i][j][1] + b4.y));
          pk.z = f2bf(gelu_f(acc[i][j][2] + b4.z));
          pk.w = f2bf(gelu_f(acc[i][j][3] + b4.w));
          *reinterpret_cast<ushort4*>(&outb[(size_t)row * (size_t)N + col0]) = pk;
        } else {  // EPI 1: f32 + bias + residual
          const float4 b4 = *reinterpret_cast<const float4*>(&bias[col0]);
          const size_t idx = (size_t)row * (size_t)N + col0;
          const float4 r4 = *reinterpret_cast<const float4*>(&resid[idx]);
          float4 o4;
          o4.x = acc[i][j][0] + b4.x + r4.x;
          o4.y = acc[i][j][1] + b4.y + r4.y;
          o4.z = acc[i][j][2] + b4.z + r4.z;
          o4.w = acc[i][j][3] + b4.w + r4.w;
          *reinterpret_cast<float4*>(&outf[idx]) = o4;
        }
      }
    }
  }
}
#undef MFMA_SUB
#undef READ_AF
#undef READ_BF
#undef LGKM
#undef MEMFENCE
#undef BAR

// ---------------- fused flash attention (128 Q-rows / block) ----------------
// LDS-staged K/V double-buffer (round-7 direct-global variant was latency-
// bound: MfmaUtil 10%, nothing busy — staging decouples fetch latency from
// the QK->softmax->PV chain). V-fragment reads hoisted out of the g-loop
// (round 6 re-read them per g: 16 ds_read_b128/kt -> 8).
__global__ __launch_bounds__(256) void attn_kernel(
    const unsigned short* __restrict__ Q, const unsigned short* __restrict__ Kc,
    const unsigned short* __restrict__ Vg, const int* __restrict__ mask,
    unsigned short* __restrict__ ctx) {
  __shared__ __align__(16) unsigned short Ks[2][64 * 64];
  __shared__ __align__(16) unsigned short Vs[2][64 * 64];
  __shared__ __align__(16) unsigned short Ps[4][16 * 72];
  __shared__ float maskf[1024];
  const int t = threadIdx.x;
  const int bh = blockIdx.x;
  const int qt = blockIdx.y;
  const int b = bh >> 4, h = bh & 15;
  const int lane = t & 63, wv = t >> 6, l15 = lane & 15, quad = lane >> 4;
  const int lr = lane >> 3;
  const int cs = (lane & 7) ^ lr;
  const unsigned short* Qp = Q + ((size_t)bh << 16);
  const unsigned short* Kp = Kc + ((size_t)bh << 16);
  const unsigned short* Vp = Vg + ((size_t)bh << 16);
  const int seg0 = wv * 2, seg1 = wv * 2 + 1;
  const int r0 = seg0 * 8 + lr, r1 = seg1 * 8 + lr;

  for (int i = t; i < 1024; i += 256)
    maskf[i] = mask[b * 1024 + i] ? -8.f : -INFINITY;

  short8 qf[2][2];
#pragma unroll
  for (int g = 0; g < 2; ++g)
#pragma unroll
    for (int hh = 0; hh < 2; ++hh)
      qf[g][hh] = *reinterpret_cast<const short8*>(
          &Qp[(size_t)(qt * 128 + wv * 32 + g * 16 + l15) * 64 + hh * 32 + quad * 8]);

  gll16(&Kp[r0 * 64 + cs * 8], &Ks[0][seg0 * 512]);
  gll16(&Kp[r1 * 64 + cs * 8], &Ks[0][seg1 * 512]);
  gll16(&Vp[r0 * 1024 + cs * 8], &Vs[0][seg0 * 512]);
  gll16(&Vp[r1 * 1024 + cs * 8], &Vs[0][seg1 * 512]);

  const int sw0 = ((quad ^ (l15 & 7)) << 3);
  const int sw1 = (((quad + 4) ^ (l15 & 7)) << 3);
  const f32x4 zero = {0.f, 0.f, 0.f, 0.f};
  float ps[2][4];
  f32x4 o[2][4];
#pragma unroll
  for (int g = 0; g < 2; ++g)
#pragma unroll
    for (int j = 0; j < 4; ++j) { o[g][j] = zero; ps[g][j] = 0.f; }

  unsigned short* Pw = Ps[wv];
  for (int kt = 0; kt < 16; ++kt) {
    __syncthreads();
    const int cur = kt & 1;
    if (kt < 15) {
      const int nb = cur ^ 1;
      gll16(&Kp[((kt + 1) * 64 + r0) * 64 + cs * 8], &Ks[nb][seg0 * 512]);
      gll16(&Kp[((kt + 1) * 64 + r1) * 64 + cs * 8], &Ks[nb][seg1 * 512]);
      gll16(&Vp[r0 * 1024 + (kt + 1) * 64 + cs * 8], &Vs[nb][seg0 * 512]);
      gll16(&Vp[r1 * 1024 + (kt + 1) * 64 + cs * 8], &Vs[nb][seg1 * 512]);
    }
    float madd[4];
    short8 kf[4][2], vf[4][2];
#pragma unroll
    for (int nt = 0; nt < 4; ++nt) {
      const int row = (nt * 16 + l15) * 64;
      kf[nt][0] = *reinterpret_cast<const short8*>(&Ks[cur][row + sw0]);
      kf[nt][1] = *reinterpret_cast<const short8*>(&Ks[cur][row + sw1]);
      vf[nt][0] = *reinterpret_cast<const short8*>(&Vs[cur][row + sw0]);
      vf[nt][1] = *reinterpret_cast<const short8*>(&Vs[cur][row + sw1]);
      madd[nt] = maskf[kt * 64 + nt * 16 + l15];
    }
#pragma unroll
    for (int g = 0; g < 2; ++g) {
      f32x4 s4[4];
      // dependency split: 4 independent k-half-0 MFMAs, then the 4 half-1s
#pragma unroll
      for (int nt = 0; nt < 4; ++nt)
        s4[nt] = __builtin_amdgcn_mfma_f32_16x16x32_bf16(qf[g][0], kf[nt][0], zero, 0, 0, 0);
#pragma unroll
      for (int nt = 0; nt < 4; ++nt)
        s4[nt] = __builtin_amdgcn_mfma_f32_16x16x32_bf16(qf[g][1], kf[nt][1], s4[nt], 0, 0, 0);
#pragma unroll
      for (int nt = 0; nt < 4; ++nt) {
#pragma unroll
        for (int r = 0; r < 4; ++r) {
          float p = __expf(s4[nt][r] + madd[nt]);
          ps[g][r] += p;
          Pw[(quad * 4 + r) * 72 + nt * 16 + l15] = f2bf(p);
        }
      }
      // C-layout -> A-layout via wave-private LDS (in-order per-wave DS pipe)
      short8 pf0 = *reinterpret_cast<const short8*>(&Pw[l15 * 72 + quad * 8]);
      short8 pf1 = *reinterpret_cast<const short8*>(&Pw[l15 * 72 + 32 + quad * 8]);
#pragma unroll
      for (int nt = 0; nt < 4; ++nt)
        o[g][nt] = __builtin_amdgcn_mfma_f32_16x16x32_bf16(pf0, vf[nt][0], o[g][nt], 0, 0, 0);
#pragma unroll
      for (int nt = 0; nt < 4; ++nt)
        o[g][nt] = __builtin_amdgcn_mfma_f32_16x16x32_bf16(pf1, vf[nt][1], o[g][nt], 0, 0, 0);
    }
  }

#pragma unroll
  for (int g = 0; g < 2; ++g)
#pragma unroll
    for (int r = 0; r < 4; ++r) {
      float v = ps[g][r];
#pragma unroll
      for (int off = 8; off >= 1; off >>= 1) v += __shfl_xor(v, off, 64);
      const float inv = 1.f / v;
      const int srow = qt * 128 + wv * 32 + g * 16 + quad * 4 + r;
#pragma unroll
      for (int nt = 0; nt < 4; ++nt) {
        const int dh = nt * 16 + l15;
        ctx[((size_t)b << 20) + ((size_t)srow << 10) + (h << 6) + dh] =
            f2bf(o[g][nt][r] * inv);
      }
    }
}

// ---------------- layer norm (block per row, D=1024) ----------------
__global__ __launch_bounds__(256) void ln_kernel(float* __restrict__ y,
                                                 const float* __restrict__ g,
                                                 const float* __restrict__ be,
                                                 unsigned short* __restrict__ hb) {
  __shared__ float sm[8];
  const int t = threadIdx.x;
  const size_t row = blockIdx.x;
  float* yr = y + (row << 10);
  float v[4];
#pragma unroll
  for (int i = 0; i < 4; ++i) v[i] = yr[t + (i << 8)];
  float s = v[0] + v[1] + v[2] + v[3];
#pragma unroll
  for (int off = 32; off >= 1; off >>= 1) s += __shfl_xor(s, off, 64);
  if ((t & 63) == 0) sm[t >> 6] = s;
  __syncthreads();
  float mu = (sm[0] + sm[1] + sm[2] + sm[3]) * (1.f / 1024.f);
  float q = 0.f;
#pragma unroll
  for (int i = 0; i < 4; ++i) { float d = v[i] - mu; q += d * d; }
#pragma unroll
  for (int off = 32; off >= 1; off >>= 1) q += __shfl_xor(q, off, 64);
  if ((t & 63) == 0) sm[4 + (t >> 6)] = q;
  __syncthreads();
  float var = (sm[4] + sm[5] + sm[6] + sm[7]) * (1.f / 1024.f);
  float rs = rsqrtf(var + 1e-12f);
#pragma unroll
  for (int i = 0; i < 4; ++i) {
    int c = t + (i << 8);
    float o = (v[i] - mu) * rs * g[c] + be[c];
    yr[c] = o;
    if (hb) hb[(row << 10) + c] = f2bf(o);
  }
}

extern "C" void kernel_launch(void* const* d_in, const int* in_sizes, int n_in,
                              void* d_out, int out_size, void* d_ws, size_t ws_size,
                              hipStream_t stream) {
  const float* x   = (const float*)d_in[0];
  const int*   msk = (const int*)d_in[1];
  const float* Wq  = (const float*)d_in[2];
  const float* bq  = (const float*)d_in[3];
  const float* Wk  = (const float*)d_in[4];
  const float* bk  = (const float*)d_in[5];
  const float* Wv  = (const float*)d_in[6];
  const float* bv  = (const float*)d_in[7];
  const float* Wo  = (const float*)d_in[8];
  const float* bo  = (const float*)d_in[9];
  const float* g1  = (const float*)d_in[10];
  const float* be1 = (const float*)d_in[11];
  const float* W1  = (const float*)d_in[12];
  const float* b1  = (const float*)d_in[13];
  const float* W2  = (const float*)d_in[14];
  const float* b2  = (const float*)d_in[15];
  const float* g2  = (const float*)d_in[16];
  const float* be2 = (const float*)d_in[17];
  float* out = (float*)d_out;

  unsigned short* Wqb = (unsigned short*)d_ws;   // Wq|Wk contiguous = fused QK B
  unsigned short* Wvb = Wqb + (2u << 20);
  unsigned short* Wob = Wvb + (1u << 20);
  unsigned short* W1b = Wob + (1u << 20);
  unsigned short* W2b = W1b + (4u << 20);
  unsigned short* xb  = W2b + (4u << 20);
  unsigned short* qb  = xb + (8u << 20);   // q|k contiguous (chunk<<23)
  unsigned short* vb  = qb + (16u << 20);  // V stored [b,h,dh,s]
  unsigned short* ctx = xb;                // reuse (xb dead after QKV GEMMs)
  unsigned short* ffb = xb;                // 32M elems spanning xb+q+k+v
  float* y1 = (float*)(qb + (24u << 20));
  unsigned short* hb = (unsigned short*)(y1 + (8u << 20));

  dim3 blk(256), blk5(512);
  // all conversions, one dispatch
  cvt_all<<<dim3(20480), blk, 0, stream>>>(Wq, Wk, Wv, Wo, W1, W2, x, (unsigned short*)d_ws);
  // QK fused projection; V separate (transposed pack, non-swapped)
  gemm_big<5, 256, true><<<dim3(8, 32), blk5, 0, stream>>>(xb, Wqb, bq, bk, 1024, 2048,
                                                           nullptr, qb, nullptr);
  gemm_big<4, 128, false><<<dim3(8, 32), blk5, 0, stream>>>(xb, Wvb, bv, nullptr, 1024, 1024,
                                                            nullptr, vb, nullptr);
  attn_kernel<<<dim3(128, 8), blk, 0, stream>>>(qb, qb + (8u << 20), vb, msk, ctx);
  // output projection + residual
  gemm_big<1, 128, true><<<dim3(8, 32), blk5, 0, stream>>>(ctx, Wob, bo, nullptr, 1024, 1024,
                                                           x, nullptr, y1);
  ln_kernel<<<dim3(8192), blk, 0, stream>>>(y1, g1, be1, hb);
  // FFN
  gemm_big<2, 256, true><<<dim3(16, 32), blk5, 0, stream>>>(hb, W1b, b1, nullptr, 1024, 4096,
                                                            nullptr, ffb, nullptr);
  gemm_big<1, 128, true><<<dim3(8, 32), blk5, 0, stream>>>(ffb, W2b, b2, nullptr, 4096, 1024,
                                                           y1, nullptr, out);
  ln_kernel<<<dim3(8192), blk, 0, stream>>>(out, g2, be2, nullptr);
}

// Round 9
// 468.556 us; speedup vs baseline: 1.1343x; 1.0566x over previous
//
#include <hip/hip_runtime.h>
#include <math.h>

typedef __attribute__((ext_vector_type(8))) short short8;
typedef __attribute__((ext_vector_type(4))) float f32x4;

__device__ __forceinline__ unsigned short f2bf(float f) {
  unsigned int u = __float_as_uint(f);
  u += 0x7fffu + ((u >> 16) & 1u);
  return (unsigned short)(u >> 16);
}

// branch-free erf-based gelu (A&S 7.1.26, |err|<1.5e-7)
__device__ __forceinline__ float gelu_f(float v) {
  float xa = fabsf(v) * 0.70710678118f;
  float t = __builtin_amdgcn_rcpf(1.f + 0.3275911f * xa);
  float p = t * (0.254829592f +
            t * (-0.284496736f +
            t * (1.421413741f +
            t * (-1.453152027f + t * 1.061405429f))));
  float erfa = 1.f - p * __expf(-xa * xa);
  return 0.5f * v * (1.f + copysignf(erfa, v));
}

// async global->LDS, 16B per lane. LDS dst is wave-uniform base; HW deposits
// lane i at base + i*16. Global side addresses are per-lane arbitrary.
__device__ __forceinline__ void gll16(const unsigned short* g, unsigned short* l) {
  __builtin_amdgcn_global_load_lds(
      (const __attribute__((address_space(1))) unsigned int*)(uintptr_t)g,
      (__attribute__((address_space(3))) unsigned int*)(uintptr_t)l, 16, 0, 0);
}

// ---------------- all fp32 -> bf16 conversions in ONE dispatch ----------------
__global__ __launch_bounds__(256) void cvt_all(
    const float* __restrict__ Wq, const float* __restrict__ Wk,
    const float* __restrict__ Wv, const float* __restrict__ Wo,
    const float* __restrict__ W1, const float* __restrict__ W2,
    const float* __restrict__ x, unsigned short* __restrict__ ws) {
  const int bi = blockIdx.x;
  const float* in;
  unsigned short* out;
  int i;
  if (bi < 4096) {
    const int m = bi >> 10;
    in = (m == 0) ? Wq : (m == 1) ? Wk : (m == 2) ? Wv : Wo;
    out = ws + (size_t)m * (1u << 20);
    i = (bi & 1023) * 256 + threadIdx.x;
  } else if (bi < 8192) {
    in = W1; out = ws + (4u << 20); i = (bi - 4096) * 256 + threadIdx.x;
  } else if (bi < 12288) {
    in = W2; out = ws + (8u << 20); i = (bi - 8192) * 256 + threadIdx.x;
  } else {
    in = x; out = ws + (12u << 20); i = (bi - 12288) * 256 + threadIdx.x;
  }
  float4 f = reinterpret_cast<const float4*>(in)[i];
  ushort4 o;
  o.x = f2bf(f.x); o.y = f2bf(f.y); o.z = f2bf(f.z); o.w = f2bf(f.w);
  reinterpret_cast<ushort4*>(out)[i] = o;
}

// ---------------- 256-wide pipelined GEMM: C = A[M,K] * B[N,K]^T ------------
// BM=256, BK=64, 512 thr = 8 waves (2M x 4N), per-wave out 128 x (BN/4).
// ONE barrier + one vmcnt(0) per K-tile (classic dbuf; staging lands under
// this tile's compute). Intra-tile: 4 sub-phases, A-fragments register-
// pipelined (afA/afB) gated by counted lgkmcnt(4). Dependency-split MFMA
// ordering (k-half-0 cluster then k-half-1 cluster) — confirmed ~4% via
// FFN1 dur 86.9 -> 84.7 -> 83.3 across rounds 5/6/8.
// Rule #18: every inline-asm lgkmcnt is followed by sched_barrier(0).
// T2: XOR swizzle (slot ^= row&7) — pre-swizzled GLOBAL source + linear
// global_load_lds deposit + same-XOR ds_read (both-sides involution).
#define MFMA_SUB(f0, SA)                                                      \
  {                                                                           \
    __builtin_amdgcn_s_setprio(1);                                            \
    _Pragma("unroll") for (int fi = 0; fi < 2; ++fi) {                        \
      _Pragma("unroll") for (int j = 0; j < NREP; ++j) {                      \
        if constexpr (SWAP) {                                                 \
          acc[(f0) + fi][j] = __builtin_amdgcn_mfma_f32_16x16x32_bf16(        \
              bf[j][0], SA[fi][0], acc[(f0) + fi][j], 0, 0, 0);               \
        } else {                                                              \
          acc[(f0) + fi][j] = __builtin_amdgcn_mfma_f32_16x16x32_bf16(        \
              SA[fi][0], bf[j][0], acc[(f0) + fi][j], 0, 0, 0);               \
        }                                                                     \
      }                                                                       \
    }                                                                         \
    _Pragma("unroll") for (int fi = 0; fi < 2; ++fi) {                        \
      _Pragma("unroll") for (int j = 0; j < NREP; ++j) {                      \
        if constexpr (SWAP) {                                                 \
          acc[(f0) + fi][j] = __builtin_amdgcn_mfma_f32_16x16x32_bf16(        \
              bf[j][1], SA[fi][1], acc[(f0) + fi][j], 0, 0, 0);               \
        } else {                                                              \
          acc[(f0) + fi][j] = __builtin_amdgcn_mfma_f32_16x16x32_bf16(        \
              SA[fi][1], bf[j][1], acc[(f0) + fi][j], 0, 0, 0);               \
        }                                                                     \
      }                                                                       \
    }                                                                         \
    __builtin_amdgcn_s_setprio(0);                                            \
  }

// A-frag f sits at rows f*16 (f = 0..7), LDS row stride 64 elems.
#define READ_AF(SET, f0)                                                      \
  {                                                                           \
    SET[0][0] = *reinterpret_cast<const short8*>(                             \
        &Asc[abase + ((f0) * 16) * 64 + s0]);                                 \
    SET[0][1] = *reinterpret_cast<const short8*>(                             \
        &Asc[abase + ((f0) * 16) * 64 + s1]);                                 \
    SET[1][0] = *reinterpret_cast<const short8*>(                             \
        &Asc[abase + ((f0) * 16 + 16) * 64 + s0]);                            \
    SET[1][1] = *reinterpret_cast<const short8*>(                             \
        &Asc[abase + ((f0) * 16 + 16) * 64 + s1]);                            \
  }

#define READ_BF                                                               \
  _Pragma("unroll") for (int j = 0; j < NREP; ++j) {                          \
    bf[j][0] = *reinterpret_cast<const short8*>(                              \
        &Bsc[bbase + (j * 16) * 64 + s0]);                                    \
    bf[j][1] = *reinterpret_cast<const short8*>(                              \
        &Bsc[bbase + (j * 16) * 64 + s1]);                                    \
  }

#define LGKM(n)                                                               \
  asm volatile("s_waitcnt lgkmcnt(" #n ")" ::: "memory");                     \
  __builtin_amdgcn_sched_barrier(0)

#define MEMFENCE asm volatile("" ::: "memory")
#define BAR __builtin_amdgcn_s_barrier()

template <int EPI, int BN, bool SWAP>
__global__ __launch_bounds__(512, 2) void gemm_big(
    const unsigned short* __restrict__ A, const unsigned short* __restrict__ B,
    const float* __restrict__ bias, const float* __restrict__ bias_k,
    int K, int N, const float* __restrict__ resid,
    unsigned short* __restrict__ outb, float* __restrict__ outf) {
  constexpr int WN = BN / 4;     // per-wave N span (64 or 32)
  constexpr int NREP = WN / 16;  // 4 or 2
  constexpr int BGRP = BN / 64;  // B stage groups (4 or 2)
  __shared__ __align__(16) unsigned short As[2][256 * 64];
  __shared__ __align__(16) unsigned short Bs[2][BN * 64];

  const int t = threadIdx.x;
  const int lane = t & 63, wv = t >> 6;
  const int wm = wv >> 2, wn = wv & 3;
  const int l15 = lane & 15, quad = lane >> 4;

  // XCD-contiguous raster (all grids have nwg % 8 == 0, gridDim.x pow2)
  const int gx = gridDim.x;
  const int nwg = gx * gridDim.y;
  int lin = blockIdx.y * gx + blockIdx.x;
  lin = (lin & 7) * (nwg >> 3) + (lin >> 3);
  const int gxs = 31 - __clz(gx);
  const int tn = (lin & (gx - 1)) * BN;
  const int tm = (lin >> gxs) * 256;

  // staging: global side carries the swizzle, LDS deposit is linear.
  // LDS[r][s*8] <- global(r, (s ^ (r&7))*8); read uses the same XOR.
  const int srow = lane >> 3;                   // 0..7 within wave's 8 rows
  const int scol = ((lane & 7) ^ srow) << 3;    // swizzled 8-elem slot
  const unsigned short* pA[4];
  const unsigned short* pB[BGRP];
#pragma unroll
  for (int g = 0; g < 4; ++g)
    pA[g] = &A[(size_t)(tm + g * 64 + wv * 8 + srow) * K + scol];
#pragma unroll
  for (int g = 0; g < BGRP; ++g)
    pB[g] = &B[(size_t)(tn + g * 64 + wv * 8 + srow) * K + scol];

  // read-side swizzled offsets (elems)
  const int abase = (wm * 128 + l15) * 64;
  const int bbase = (wn * WN + l15) * 64;
  const int s0 = ((quad ^ (l15 & 7)) << 3);
  const int s1 = (((quad + 4) ^ (l15 & 7)) << 3);

  const f32x4 zero = {0.f, 0.f, 0.f, 0.f};
  f32x4 acc[8][NREP];
#pragma unroll
  for (int i = 0; i < 8; ++i)
#pragma unroll
    for (int j = 0; j < NREP; ++j) acc[i][j] = zero;
  short8 afA[2][2], afB[2][2], bf[NREP][2];

  // prologue: stage tile 0 -> buf0
#pragma unroll
  for (int g = 0; g < 4; ++g) {
    gll16(pA[g], &As[0][(g * 64 + wv * 8) * 64]);
    pA[g] += 64;
  }
#pragma unroll
  for (int g = 0; g < BGRP; ++g) {
    gll16(pB[g], &Bs[0][(g * 64 + wv * 8) * 64]);
    pB[g] += 64;
  }
  asm volatile("s_waitcnt vmcnt(0)" ::: "memory");
  BAR;
  MEMFENCE;

  const int NT = K >> 6;
  for (int tt = 0; tt < NT; ++tt) {
    const unsigned short* Asc = As[tt & 1];
    const unsigned short* Bsc = Bs[tt & 1];
    unsigned short* Asn = As[(tt + 1) & 1];
    unsigned short* Bsn = Bs[(tt + 1) & 1];

    // stage tile t+1 into the other buffer (lands under this tile's compute)
    if (tt + 1 < NT) {
#pragma unroll
      for (int g = 0; g < 4; ++g) {
        gll16(pA[g], &Asn[(g * 64 + wv * 8) * 64]);
        pA[g] += 64;
      }
#pragma unroll
      for (int g = 0; g < BGRP; ++g) {
        gll16(pB[g], &Bsn[(g * 64 + wv * 8) * 64]);
        pB[g] += 64;
      }
    }

    // tile-top reads: all B frags + A set A (frags 0,1)
    READ_BF;
    READ_AF(afA, 0);
    // sub 0: prefetch frags 2,3 -> setB; MFMA frags 0,1 (gate: bf+afA landed)
    READ_AF(afB, 2);
    LGKM(4);
    MFMA_SUB(0, afA);
    // sub 1: prefetch frags 4,5 -> setA; MFMA frags 2,3
    READ_AF(afA, 4);
    LGKM(4);
    MFMA_SUB(2, afB);
    // sub 2: prefetch frags 6,7 -> setB; MFMA frags 4,5
    READ_AF(afB, 6);
    LGKM(4);
    MFMA_SUB(4, afA);
    // sub 3: MFMA frags 6,7 (all reads must be done)
    LGKM(0);
    MFMA_SUB(6, afB);

    if (tt + 1 < NT) {
      asm volatile("s_waitcnt vmcnt(0)" ::: "memory");  // t+1 deposits landed
      BAR;  // all waves done reading cur + deposits visible
      MEMFENCE;
    }
  }

  // ---- epilogue ----
  if constexpr (!SWAP) {
    // EPI 4: V epilogue — regs hold 4 consecutive tokens; pack for [b,h,dh,s]
    const int rb2 = tm + wm * 128 + (quad << 2);
    const int cb2 = tn + wn * WN + l15;
#pragma unroll
    for (int i = 0; i < 8; ++i) {
      const int row0 = rb2 + i * 16;
#pragma unroll
      for (int j = 0; j < NREP; ++j) {
        const int col = cb2 + j * 16;
        const float bcol = bias[col];
        const int h = col >> 6, dh = col & 63;
        const int b = row0 >> 10, s0r = row0 & 1023;
        ushort4 pk;
        pk.x = f2bf(acc[i][j][0] + bcol);
        pk.y = f2bf(acc[i][j][1] + bcol);
        pk.z = f2bf(acc[i][j][2] + bcol);
        pk.w = f2bf(acc[i][j][3] + bcol);
        *reinterpret_cast<ushort4*>(
            &outb[(((size_t)((b << 4) + h)) << 16) + (dh << 10) + s0r]) = pk;
      }
    }
  } else {
    const int rb = tm + wm * 128 + l15;
    const int cb = tn + wn * WN + (quad << 2);
#pragma unroll
    for (int i = 0; i < 8; ++i) {
      const int row = rb + i * 16;
#pragma unroll
      for (int j = 0; j < NREP; ++j) {
        const int col0 = cb + j * 16;
        if constexpr (EPI == 5) {
          const int chunk = col0 >> 10;  // 0=Q, 1=K
          const int colc = col0 & 1023;
          const float4 b4 = *reinterpret_cast<const float4*>(
              &(chunk == 0 ? bias : bias_k)[colc]);
          const float sc = (chunk == 0) ? 0.125f : 1.f;
          const int h = colc >> 6, dh = colc & 63;
          const int b = row >> 10, s = row & 1023;
          ushort4 pk;
          pk.x = f2bf((acc[i][j][0] + b4.x) * sc);
          pk.y = f2bf((acc[i][j][1] + b4.y) * sc);
          pk.z = f2bf((acc[i][j][2] + b4.z) * sc);
          pk.w = f2bf((acc[i][j][3] + b4.w) * sc);
          *reinterpret_cast<ushort4*>(
              &outb[((size_t)chunk << 23) + (((size_t)((b << 4) + h)) << 16) +
                    (s << 6) + dh]) = pk;
        } else if constexpr (EPI == 2) {
          const float4 b4 = *reinterpret_cast<const float4*>(&bias[col0]);
          ushort4 pk;
          pk.x = f2bf(gelu_f(acc[i][j][0] + b4.x));
          pk.y = f2bf(gelu_f(acc[i][j][1] + b4.y));
          pk.z = f2bf(gelu_f(acc[i][j][2] + b4.z));
          pk.w = f2bf(gelu_f(acc[i][j][3] + b4.w));
          *reinterpret_cast<ushort4*>(&outb[(size_t)row * (size_t)N + col0]) = pk;
        } else {  // EPI 1: f32 + bias + residual
          const float4 b4 = *reinterpret_cast<const float4*>(&bias[col0]);
          const size_t idx = (size_t)row * (size_t)N + col0;
          const float4 r4 = *reinterpret_cast<const float4*>(&resid[idx]);
          float4 o4;
          o4.x = acc[i][j][0] + b4.x + r4.x;
          o4.y = acc[i][j][1] + b4.y + r4.y;
          o4.z = acc[i][j][2] + b4.z + r4.z;
          o4.w = acc[i][j][3] + b4.w + r4.w;
          *reinterpret_cast<float4*>(&outf[idx]) = o4;
        }
      }
    }
  }
}
#undef MFMA_SUB
#undef READ_AF
#undef READ_BF
#undef LGKM
#undef MEMFENCE
#undef BAR

// ---------------- fused flash attention (128 Q-rows / block) ----------------
// Round-5 configuration restored verbatim (the 473 us run): LDS-staged K/V
// double-buffer, V-fragments read per-g inside the PV loop (short register
// lifetimes), paired MFMA ordering. R6's dep-split and R8's V-hoist both
// correlated with total regressions (register pressure in a 4-wave kernel
// that relies on TLP to hide staging latency).
__global__ __launch_bounds__(256) void attn_kernel(
    const unsigned short* __restrict__ Q, const unsigned short* __restrict__ Kc,
    const unsigned short* __restrict__ Vg, const int* __restrict__ mask,
    unsigned short* __restrict__ ctx) {
  __shared__ __align__(16) unsigned short Ks[2][64 * 64];
  __shared__ __align__(16) unsigned short Vs[2][64 * 64];
  __shared__ __align__(16) unsigned short Ps[4][16 * 72];
  __shared__ float maskf[1024];
  const int t = threadIdx.x;
  const int bh = blockIdx.x;
  const int qt = blockIdx.y;
  const int b = bh >> 4, h = bh & 15;
  const int lane = t & 63, wv = t >> 6, l15 = lane & 15, quad = lane >> 4;
  const int lr = lane >> 3;
  const int cs = (lane & 7) ^ lr;
  const unsigned short* Qp = Q + ((size_t)bh << 16);
  const unsigned short* Kp = Kc + ((size_t)bh << 16);
  const unsigned short* Vp = Vg + ((size_t)bh << 16);
  const int seg0 = wv * 2, seg1 = wv * 2 + 1;
  const int r0 = seg0 * 8 + lr, r1 = seg1 * 8 + lr;

  for (int i = t; i < 1024; i += 256)
    maskf[i] = mask[b * 1024 + i] ? -8.f : -INFINITY;

  short8 qf[2][2];
#pragma unroll
  for (int g = 0; g < 2; ++g)
#pragma unroll
    for (int hh = 0; hh < 2; ++hh)
      qf[g][hh] = *reinterpret_cast<const short8*>(
          &Qp[(size_t)(qt * 128 + wv * 32 + g * 16 + l15) * 64 + hh * 32 + quad * 8]);

  gll16(&Kp[r0 * 64 + cs * 8], &Ks[0][seg0 * 512]);
  gll16(&Kp[r1 * 64 + cs * 8], &Ks[0][seg1 * 512]);
  gll16(&Vp[r0 * 1024 + cs * 8], &Vs[0][seg0 * 512]);
  gll16(&Vp[r1 * 1024 + cs * 8], &Vs[0][seg1 * 512]);

  const int sw0 = ((quad ^ (l15 & 7)) << 3);
  const int sw1 = (((quad + 4) ^ (l15 & 7)) << 3);
  const f32x4 zero = {0.f, 0.f, 0.f, 0.f};
  float ps[2][4];
  f32x4 o[2][4];
#pragma unroll
  for (int g = 0; g < 2; ++g)
#pragma unroll
    for (int j = 0; j < 4; ++j) { o[g][j] = zero; ps[g][j] = 0.f; }

  unsigned short* Pw = Ps[wv];
  for (int kt = 0; kt < 16; ++kt) {
    __syncthreads();
    const int cur = kt & 1;
    if (kt < 15) {
      const int nb = cur ^ 1;
      gll16(&Kp[((kt + 1) * 64 + r0) * 64 + cs * 8], &Ks[nb][seg0 * 512]);
      gll16(&Kp[((kt + 1) * 64 + r1) * 64 + cs * 8], &Ks[nb][seg1 * 512]);
      gll16(&Vp[r0 * 1024 + (kt + 1) * 64 + cs * 8], &Vs[nb][seg0 * 512]);
      gll16(&Vp[r1 * 1024 + (kt + 1) * 64 + cs * 8], &Vs[nb][seg1 * 512]);
    }
    float madd[4];
    short8 kf[4][2];
#pragma unroll
    for (int nt = 0; nt < 4; ++nt) {
      const int row = (nt * 16 + l15) * 64;
      kf[nt][0] = *reinterpret_cast<const short8*>(&Ks[cur][row + sw0]);
      kf[nt][1] = *reinterpret_cast<const short8*>(&Ks[cur][row + sw1]);
      madd[nt] = maskf[kt * 64 + nt * 16 + l15];
    }
#pragma unroll
    for (int g = 0; g < 2; ++g) {
      f32x4 s4[4];
#pragma unroll
      for (int nt = 0; nt < 4; ++nt) {
        s4[nt] = __builtin_amdgcn_mfma_f32_16x16x32_bf16(qf[g][0], kf[nt][0], zero, 0, 0, 0);
        s4[nt] = __builtin_amdgcn_mfma_f32_16x16x32_bf16(qf[g][1], kf[nt][1], s4[nt], 0, 0, 0);
      }
#pragma unroll
      for (int nt = 0; nt < 4; ++nt) {
#pragma unroll
        for (int r = 0; r < 4; ++r) {
          float p = __expf(s4[nt][r] + madd[nt]);
          ps[g][r] += p;
          Pw[(quad * 4 + r) * 72 + nt * 16 + l15] = f2bf(p);
        }
      }
      // C-layout -> A-layout via wave-private LDS (in-order per-wave DS pipe)
      short8 pf0 = *reinterpret_cast<const short8*>(&Pw[l15 * 72 + quad * 8]);
      short8 pf1 = *reinterpret_cast<const short8*>(&Pw[l15 * 72 + 32 + quad * 8]);
#pragma unroll
      for (int nt = 0; nt < 4; ++nt) {
        const int row = (nt * 16 + l15) * 64;
        short8 vf0 = *reinterpret_cast<const short8*>(&Vs[cur][row + sw0]);
        short8 vf1 = *reinterpret_cast<const short8*>(&Vs[cur][row + sw1]);
        o[g][nt] = __builtin_amdgcn_mfma_f32_16x16x32_bf16(pf0, vf0, o[g][nt], 0, 0, 0);
        o[g][nt] = __builtin_amdgcn_mfma_f32_16x16x32_bf16(pf1, vf1, o[g][nt], 0, 0, 0);
      }
    }
  }

#pragma unroll
  for (int g = 0; g < 2; ++g)
#pragma unroll
    for (int r = 0; r < 4; ++r) {
      float v = ps[g][r];
#pragma unroll
      for (int off = 8; off >= 1; off >>= 1) v += __shfl_xor(v, off, 64);
      const float inv = 1.f / v;
      const int srow = qt * 128 + wv * 32 + g * 16 + quad * 4 + r;
#pragma unroll
      for (int nt = 0; nt < 4; ++nt) {
        const int dh = nt * 16 + l15;
        ctx[((size_t)b << 20) + ((size_t)srow << 10) + (h << 6) + dh] =
            f2bf(o[g][nt][r] * inv);
      }
    }
}

// ---------------- layer norm (block per row, D=1024, float4-vectorized) -----
// G13: 1 dwordx4 load + float4 g/b loads + float4 y-store + ushort4 hb-store
// per thread (16B/lane coalescing sweet spot) instead of 4 scalar dword
// loads/stores. Thread t owns elements [4t, 4t+3] of the row.
__global__ __launch_bounds__(256) void ln_kernel(float* __restrict__ y,
                                                 const float* __restrict__ g,
                                                 const float* __restrict__ be,
                                                 unsigned short* __restrict__ hb) {
  __shared__ float sm[8];
  const int t = threadIdx.x;
  const size_t row = blockIdx.x;
  float* yr = y + (row << 10);
  const float4 v = reinterpret_cast<const float4*>(yr)[t];
  float s = v.x + v.y + v.z + v.w;
#pragma unroll
  for (int off = 32; off >= 1; off >>= 1) s += __shfl_xor(s, off, 64);
  if ((t & 63) == 0) sm[t >> 6] = s;
  __syncthreads();
  float mu = (sm[0] + sm[1] + sm[2] + sm[3]) * (1.f / 1024.f);
  const float dx = v.x - mu, dy = v.y - mu, dz = v.z - mu, dw = v.w - mu;
  float q = dx * dx + dy * dy + dz * dz + dw * dw;
#pragma unroll
  for (int off = 32; off >= 1; off >>= 1) q += __shfl_xor(q, off, 64);
  if ((t & 63) == 0) sm[4 + (t >> 6)] = q;
  __syncthreads();
  float var = (sm[4] + sm[5] + sm[6] + sm[7]) * (1.f / 1024.f);
  float rs = rsqrtf(var + 1e-12f);
  const float4 g4 = reinterpret_cast<const float4*>(g)[t];
  const float4 b4 = reinterpret_cast<const float4*>(be)[t];
  float4 o4;
  o4.x = dx * rs * g4.x + b4.x;
  o4.y = dy * rs * g4.y + b4.y;
  o4.z = dz * rs * g4.z + b4.z;
  o4.w = dw * rs * g4.w + b4.w;
  reinterpret_cast<float4*>(yr)[t] = o4;
  if (hb) {
    ushort4 pk;
    pk.x = f2bf(o4.x); pk.y = f2bf(o4.y); pk.z = f2bf(o4.z); pk.w = f2bf(o4.w);
    reinterpret_cast<ushort4*>(hb + (row << 10))[t] = pk;
  }
}

extern "C" void kernel_launch(void* const* d_in, const int* in_sizes, int n_in,
                              void* d_out, int out_size, void* d_ws, size_t ws_size,
                              hipStream_t stream) {
  const float* x   = (const float*)d_in[0];
  const int*   msk = (const int*)d_in[1];
  const float* Wq  = (const float*)d_in[2];
  const float* bq  = (const float*)d_in[3];
  const float* Wk  = (const float*)d_in[4];
  const float* bk  = (const float*)d_in[5];
  const float* Wv  = (const float*)d_in[6];
  const float* bv  = (const float*)d_in[7];
  const float* Wo  = (const float*)d_in[8];
  const float* bo  = (const float*)d_in[9];
  const float* g1  = (const float*)d_in[10];
  const float* be1 = (const float*)d_in[11];
  const float* W1  = (const float*)d_in[12];
  const float* b1  = (const float*)d_in[13];
  const float* W2  = (const float*)d_in[14];
  const float* b2  = (const float*)d_in[15];
  const float* g2  = (const float*)d_in[16];
  const float* be2 = (const float*)d_in[17];
  float* out = (float*)d_out;

  unsigned short* Wqb = (unsigned short*)d_ws;   // Wq|Wk contiguous = fused QK B
  unsigned short* Wvb = Wqb + (2u << 20);
  unsigned short* Wob = Wvb + (1u << 20);
  unsigned short* W1b = Wob + (1u << 20);
  unsigned short* W2b = W1b + (4u << 20);
  unsigned short* xb  = W2b + (4u << 20);
  unsigned short* qb  = xb + (8u << 20);   // q|k contiguous (chunk<<23)
  unsigned short* vb  = qb + (16u << 20);  // V stored [b,h,dh,s]
  unsigned short* ctx = xb;                // reuse (xb dead after QKV GEMMs)
  unsigned short* ffb = xb;                // 32M elems spanning xb+q+k+v
  float* y1 = (float*)(qb + (24u << 20));
  unsigned short* hb = (unsigned short*)(y1 + (8u << 20));

  dim3 blk(256), blk5(512);
  // all conversions, one dispatch
  cvt_all<<<dim3(20480), blk, 0, stream>>>(Wq, Wk, Wv, Wo, W1, W2, x, (unsigned short*)d_ws);
  // QK fused projection; V separate (transposed pack, non-swapped)
  gemm_big<5, 256, true><<<dim3(8, 32), blk5, 0, stream>>>(xb, Wqb, bq, bk, 1024, 2048,
                                                           nullptr, qb, nullptr);
  gemm_big<4, 128, false><<<dim3(8, 32), blk5, 0, stream>>>(xb, Wvb, bv, nullptr, 1024, 1024,
                                                            nullptr, vb, nullptr);
  attn_kernel<<<dim3(128, 8), blk, 0, stream>>>(qb, qb + (8u << 20), vb, msk, ctx);
  // output projection + residual
  gemm_big<1, 128, true><<<dim3(8, 32), blk5, 0, stream>>>(ctx, Wob, bo, nullptr, 1024, 1024,
                                                           x, nullptr, y1);
  ln_kernel<<<dim3(8192), blk, 0, stream>>>(y1, g1, be1, hb);
  // FFN
  gemm_big<2, 256, true><<<dim3(16, 32), blk5, 0, stream>>>(hb, W1b, b1, nullptr, 1024, 4096,
                                                            nullptr, ffb, nullptr);
  gemm_big<1, 128, true><<<dim3(8, 32), blk5, 0, stream>>>(ffb, W2b, b2, nullptr, 4096, 1024,
                                                           y1, nullptr, out);
  ln_kernel<<<dim3(8192), blk, 0, stream>>>(out, g2, be2, nullptr);
}